// Round 6
// baseline (629.613 us; speedup 1.0000x reference)
//
#include <hip/hip_runtime.h>

// Problem constants
#define B_  8192
#define C_  64
#define K_  256
#define D_  64
#define NBT 2                  // b-tiles per block (128 rows each)
#define GX  (B_ / (128 * NBT)) // 32 blocks along b
#define BC_ (B_ * C_)
#define BN_EPS 1e-5

#define WCAP_C 1024            // per-channel referee list capacity
#define DELTA  2.5e-3f         // top-2 gap flag band (~6 sigma of pair err)

typedef _Float16 f16x8 __attribute__((ext_vector_type(8)));
typedef __fp16   h16x2 __attribute__((ext_vector_type(2)));   // cvt_pkrtz result
typedef float    f32x4 __attribute__((ext_vector_type(4)));

// XOR swizzle for [row][128B] f16 plane: kills 32-way conflict on ds_read_b128.
__device__ __forceinline__ int swz(int row, int dbyte) {
    return (row * 128 + dbyte) ^ ((row & 7) << 4);
}

// pack 8 f32 -> f16x8 via v_cvt_pkrtz (RTZ; bias incoherent in dot-gap space)
__device__ __forceinline__ f16x8 pack8(float4 a, float4 b) {
    h16x2 p0 = __builtin_amdgcn_cvt_pkrtz(a.x, a.y);
    h16x2 p1 = __builtin_amdgcn_cvt_pkrtz(a.z, a.w);
    h16x2 p2 = __builtin_amdgcn_cvt_pkrtz(b.x, b.y);
    h16x2 p3 = __builtin_amdgcn_cvt_pkrtz(b.z, b.w);
    return (f16x8){(_Float16)p0.x, (_Float16)p0.y, (_Float16)p1.x, (_Float16)p1.y,
                   (_Float16)p2.x, (_Float16)p2.y, (_Float16)p3.x, (_Float16)p3.y};
}

// ---------------------------------------------------------------------------
// Pass 1: single-pass f16 MFMA scoring, 3-stage software-pipelined k-loop.
// Block 256 thr (4 waves), 32 KiB LDS f16 centroid plane, NBT b-tiles.
// Near-ties (gap < DELTA) pushed to per-channel worklist for fp64 referee.
// ---------------------------------------------------------------------------
__global__ __launch_bounds__(256, 5) void dpq_mfma(
    const float* __restrict__ x,        // (B, C, D)
    const float* __restrict__ cent,     // (C, K, D)
    const float* __restrict__ gamma,    // (C)
    float* __restrict__ out,            // [codes BC][raw mse BC][centroids]
    float* __restrict__ part_sum,       // (C, GX)
    float* __restrict__ part_sq,        // (C, GX)
    int* __restrict__ wcount,           // (C)
    int* __restrict__ worklist)         // (C, WCAP_C) stores b
{
    __shared__ char lds[32768];
    const int c   = blockIdx.y;
    const int tid = threadIdx.x;
    const float sgn = (gamma[c] < 0.0f) ? -1.0f : 1.0f;   // fold BN sign

    // ---- stage centroids: each of 256 threads converts one k-row ----
    {
        const float* g = cent + ((size_t)c * K_ + tid) * D_;
#pragma unroll
        for (int q = 0; q < 8; ++q) {
            float4 u0 = *(const float4*)(g + q * 8);
            float4 u1 = *(const float4*)(g + q * 8 + 4);
            u0.x *= sgn; u0.y *= sgn; u0.z *= sgn; u0.w *= sgn;
            u1.x *= sgn; u1.y *= sgn; u1.z *= sgn; u1.w *= sgn;
            *(f16x8*)(lds + swz(tid, q * 16)) = pack8(u0, u1);
        }
    }
    __syncthreads();

    const int wid = tid >> 6, lane = tid & 63;
    const int col = lane & 15, grp = lane >> 4;

    float accs = 0.0f, accq = 0.0f;

#define READ(A0, A1, TT)                                                    \
    A0 = *(const f16x8*)(lds + swz((TT) * 16 + col,      grp * 16));        \
    A1 = *(const f16x8*)(lds + swz((TT) * 16 + col, 64 + grp * 16));

#define MFMA2(P0, P1, A0, A1)                                               \
    P0 = (f32x4){0.f, 0.f, 0.f, 0.f};                                       \
    P0 = __builtin_amdgcn_mfma_f32_16x16x32_f16(A0, xf00, P0, 0, 0, 0);     \
    P0 = __builtin_amdgcn_mfma_f32_16x16x32_f16(A1, xf01, P0, 0, 0, 0);     \
    P1 = (f32x4){0.f, 0.f, 0.f, 0.f};                                       \
    P1 = __builtin_amdgcn_mfma_f32_16x16x32_f16(A0, xf10, P1, 0, 0, 0);     \
    P1 = __builtin_amdgcn_mfma_f32_16x16x32_f16(A1, xf11, P1, 0, 0, 0);

#define EPI(A0, A1, TT)                                                     \
    {                                                                       \
        const int kb = (TT) * 16 + grp * 4;                                 \
        _Pragma("unroll")                                                   \
        for (int j = 0; j < 4; ++j) {                                       \
            const float r0 = A0[j], r1 = A1[j];                             \
            accs += r0; accq = fmaf(r0, r0, accq);                          \
            sec0 = __builtin_amdgcn_fmed3f(r0, best0, sec0);                \
            const bool g0 = r0 > best0; best0 = fmaxf(best0, r0);           \
            bk0 = g0 ? kb + j : bk0;                                        \
            accs += r1; accq = fmaf(r1, r1, accq);                          \
            sec1 = __builtin_amdgcn_fmed3f(r1, best1, sec1);                \
            const bool g1 = r1 > best1; best1 = fmaxf(best1, r1);           \
            bk1 = g1 ? kb + j : bk1;                                        \
        }                                                                   \
    }

    for (int bt = 0; bt < NBT; ++bt) {
        const int b0 = (blockIdx.x * NBT + bt) * 128 + wid * 32;

        // x fragments: 2 b-subtiles x 2 d-halves
        f16x8 xf00, xf01, xf10, xf11;
        {
            const float* xr0 = x + ((size_t)(b0 + col) * C_ + c) * D_ + grp * 8;
            const float* xr1 = xr0 + 16 * (size_t)C_ * D_;
            xf00 = pack8(*(const float4*)xr0, *(const float4*)(xr0 + 4));
            xf01 = pack8(*(const float4*)(xr0 + 32), *(const float4*)(xr0 + 36));
            xf10 = pack8(*(const float4*)xr1, *(const float4*)(xr1 + 4));
            xf11 = pack8(*(const float4*)(xr1 + 32), *(const float4*)(xr1 + 36));
        }

        float best0 = -3.4e38f, best1 = -3.4e38f;
        float sec0  = -3.4e38f, sec1  = -3.4e38f;
        int   bk0 = 0, bk1 = 0;

        f16x8 a0A, a1A, a0B, a1B;
        f32x4 acA0, acA1, acB0, acB1;

        // 3-stage pipeline: phase t = { READ(t+1) | MFMA(t) | EPI(t-1) }
        READ(a0A, a1A, 0);
        READ(a0B, a1B, 1);
        MFMA2(acA0, acA1, a0A, a1A);           // t = 0
#pragma unroll
        for (int h = 1; h <= 7; ++h) {
            READ(a0A, a1A, 2 * h);             // odd phase
            MFMA2(acB0, acB1, a0B, a1B);       //   t = 2h-1
            EPI(acA0, acA1, 2 * h - 2);
            READ(a0B, a1B, 2 * h + 1);         // even phase
            MFMA2(acA0, acA1, a0A, a1A);       //   t = 2h
            EPI(acB0, acB1, 2 * h - 1);
        }
        MFMA2(acB0, acB1, a0B, a1B);           // t = 15
        EPI(acA0, acA1, 14);
        EPI(acB0, acB1, 15);

        // cross-lane top-2/argmax merge (same-col lanes differ in bits 4,5)
#pragma unroll
        for (int T = 0; T < 2; ++T) {
            float bv = T ? best1 : best0;
            float sv = T ? sec1  : sec0;
            int   bk = T ? bk1   : bk0;
#pragma unroll
            for (int m = 16; m <= 32; m <<= 1) {
                const float ov = __shfl_xor(bv, m);
                const int   ok = __shfl_xor(bk, m);
                const float os = __shfl_xor(sv, m);
                sv = fmaxf(fmaxf(sv, os), fminf(bv, ov));
                if (ov > bv || (ov == bv && ok < bk)) bk = ok;
                bv = fmaxf(bv, ov);
            }
            if (grp == 0) {
                const int b = b0 + T * 16 + col;
                const size_t idx = (size_t)b * C_ + c;
                out[idx] = (float)bk;                  // code (maybe refereed)
                out[(size_t)BC_ + idx] = bv;           // raw max (affine later)
                if (bv - sv < DELTA && worklist) {
                    const int slot = atomicAdd(&wcount[c], 1);
                    if (slot < WCAP_C) worklist[c * WCAP_C + slot] = b;
                }
            }
        }
    }

    // ---- channel sum / sumsq block reduction ----
#pragma unroll
    for (int m = 1; m <= 32; m <<= 1) {
        accs += __shfl_xor(accs, m);
        accq += __shfl_xor(accq, m);
    }
    __syncthreads();                    // plane dead; reuse LDS
    float* red = (float*)lds;
    if (lane == 0) { red[wid] = accs; red[4 + wid] = accq; }
    __syncthreads();
    if (tid == 0) {
        part_sum[c * GX + blockIdx.x] = (red[0] + red[1]) + (red[2] + red[3]);
        part_sq [c * GX + blockIdx.x] = (red[4] + red[5]) + (red[6] + red[7]);
    }
#undef READ
#undef MFMA2
#undef EPI
}

// ---------------------------------------------------------------------------
// Referee: exact fp64 re-score of flagged pairs, channel-bucketed.
// grid (64, 8): block (c, s) stages channel c's centroids (f32, bank-swizzled)
// in 64 KiB LDS once; each WAVE takes one entry (lane = 4 k's), fp64 dot.
// ---------------------------------------------------------------------------
__global__ __launch_bounds__(256) void dpq_referee(
    const float* __restrict__ x,
    const float* __restrict__ cent,
    const float* __restrict__ gamma,
    const int* __restrict__ wcount,
    const int* __restrict__ worklist,
    float* __restrict__ out)
{
    __shared__ float cl[K_ * D_];       // 64 KiB exact centroids
    const int c = blockIdx.x;
    int n = wcount[c];
    if (n > WCAP_C) n = WCAP_C;
    if (n == 0) return;
    const int t = threadIdx.x;          // 0..255 = k row to stage
    const float sgnf = (gamma[c] < 0.0f) ? -1.0f : 1.0f;

    // stage row t with d-swizzle (d ^ (k&31)) -> conflict-free lane reads
    {
        const float* g = cent + ((size_t)c * K_ + t) * D_;
#pragma unroll 8
        for (int d = 0; d < D_; ++d)
            cl[t * D_ + (d ^ (t & 31))] = g[d];
    }
    __syncthreads();

    const int wid = t >> 6, lane = t & 63;
    for (int i = blockIdx.y * 4 + wid; i < n; i += gridDim.y * 4) {
        const int b = worklist[c * WCAP_C + i];
        const float* xr = x + ((size_t)b * C_ + c) * D_;
        double bv = -1.0e300;
        int bk = 0;
#pragma unroll
        for (int q = 0; q < 4; ++q) {
            const int k = q * 64 + lane;            // ascending per lane
            const int sw = k & 31;
            double s = 0.0;
#pragma unroll 8
            for (int d = 0; d < D_; ++d)
                s += (double)xr[d] * (double)cl[k * D_ + (d ^ sw)];
            s *= (double)sgnf;
            if (s > bv) { bv = s; bk = k; }
        }
#pragma unroll
        for (int m = 1; m <= 32; m <<= 1) {
            const double ov = __shfl_xor(bv, m);
            const int   ok = __shfl_xor(bk, m);
            if (ov > bv || (ov == bv && ok < bk)) { bv = ov; bk = ok; }
        }
        if (lane == 0) {
            const size_t idx = (size_t)b * C_ + c;
            out[idx] = (float)bk;
            out[(size_t)BC_ + idx] = (float)bv;
        }
    }
}

// ---------------------------------------------------------------------------
// Per-channel BN stats on sign-folded scores.
// ---------------------------------------------------------------------------
__global__ void dpq_stats(
    const float* __restrict__ part_sum,
    const float* __restrict__ part_sq,
    const float* __restrict__ gamma,
    const float* __restrict__ beta,
    float* __restrict__ scale_out,
    float* __restrict__ shift_out)
{
    const int c = threadIdx.x;
    if (c >= C_) return;
    double s = 0.0, q = 0.0;
    for (int i = 0; i < GX; ++i) {
        s += (double)part_sum[c * GX + i];
        q += (double)part_sq [c * GX + i];
    }
    const double n    = (double)B_ * (double)K_;
    const double mean = s / n;
    const double var  = q / n - mean * mean;      // biased, matches reference
    const double sc   = fabs((double)gamma[c]) / sqrt(var + BN_EPS);
    scale_out[c] = (float)sc;
    shift_out[c] = (float)((double)beta[c] - mean * sc);
}

// ---------------------------------------------------------------------------
// Apply per-channel affine to stored raw max. gamma==0 -> constant channel.
// ---------------------------------------------------------------------------
__global__ __launch_bounds__(256) void dpq_apply(
    float* __restrict__ out,
    const float* __restrict__ scale,
    const float* __restrict__ shift)
{
    const int idx = blockIdx.x * 256 + threadIdx.x;   // over B*C, c fastest
    const int c = idx & (C_ - 1);
    const float sc = scale[c];
    const float sh = shift[c];
    if (sc == 0.0f) {
        out[idx] = 0.0f;
        out[(size_t)BC_ + idx] = sh;
    } else {
        out[(size_t)BC_ + idx] = fmaf(out[(size_t)BC_ + idx], sc, sh);
    }
}

// ---------------------------------------------------------------------------
extern "C" void kernel_launch(void* const* d_in, const int* in_sizes, int n_in,
                              void* d_out, int out_size, void* d_ws, size_t ws_size,
                              hipStream_t stream)
{
    const float* x     = (const float*)d_in[0];
    const float* cent  = (const float*)d_in[1];
    const float* gamma = (const float*)d_in[2];
    const float* beta  = (const float*)d_in[3];
    float* out = (float*)d_out;
    float* ws  = (float*)d_ws;

    // ws layout (4B units): [0,2048) part_sum | [2048,4096) part_sq
    // [4096,4160) scale | [4160,4224) shift | [4224,4288) wcount[64]
    // [4288, 4288+64*WCAP_C) worklist
    float* part_sum = ws;
    float* part_sq  = ws + 2048;
    float* scale    = ws + 4096;
    float* shift    = ws + 4160;
    int*   wcount   = (int*)(ws + 4224);
    int*   worklist = (int*)(ws + 4288);
    const size_t need = (size_t)(4288 + C_ * WCAP_C) * 4;
    if (ws_size < need) { wcount = nullptr; worklist = nullptr; }

    if (wcount)
        (void)hipMemsetAsync(wcount, 0, C_ * sizeof(int), stream);

    dim3 g1(GX, C_);   // (32, 64)
    hipLaunchKernelGGL(dpq_mfma, g1, dim3(256), 0, stream,
                       x, cent, gamma, out, part_sum, part_sq, wcount, worklist);
    if (wcount)
        hipLaunchKernelGGL(dpq_referee, dim3(C_, 8), dim3(256), 0, stream,
                           x, cent, gamma, wcount, worklist, out);
    hipLaunchKernelGGL(dpq_stats, dim3(1), dim3(64), 0, stream,
                       part_sum, part_sq, gamma, beta, scale, shift);
    hipLaunchKernelGGL(dpq_apply, dim3(BC_ / 256), dim3(256), 0, stream,
                       out, scale, shift);
    (void)hipMemcpyAsync(out + 2 * (size_t)BC_, cent,
                         (size_t)C_ * K_ * D_ * sizeof(float),
                         hipMemcpyDeviceToDevice, stream);
}